// Round 13
// baseline (218.782 us; speedup 1.0000x reference)
//
#include <hip/hip_runtime.h>
#include <hip/hip_bf16.h>
#include <hip/hip_cooperative_groups.h>

#define B_ 32
#define N_ 1024
#define F_ 128
#define ALPHA_ 0.2f
#define PSTR 72   // padded LDS row stride in bf16 elems (144 B = 9 x 16B slots)

namespace cg = cooperative_groups;

typedef __attribute__((ext_vector_type(8))) short short8_t;
typedef __attribute__((ext_vector_type(4))) short short4_t;
typedef __attribute__((ext_vector_type(4))) float f32x4;

static __device__ __forceinline__ unsigned short bf16b(float f) {
    return __bfloat16_as_ushort(__float2bfloat16(f));
}
static __device__ __forceinline__ float bf2f(unsigned short u) {
    union { unsigned u; float f; } cv; cv.u = ((unsigned)u) << 16; return cv.f;
}

#define WAIT_LGKM() asm volatile("s_waitcnt lgkmcnt(0)" ::: "memory")
#define SCHEDB()    __builtin_amdgcn_sched_barrier(0)
#define BAR()       __builtin_amdgcn_s_barrier()

// ===========================================================================
// FUSED cooperative kernel (48 KB LDS -> 3 blocks/CU headroom for coop
// validation). Phase 1: hT = bf16(feat@W^T) (feat staged bf16), s,t dots;
// first two adj tiles issued pre-GEMM. grid.sync. Phase 2: R11 attn5 body.
// ===========================================================================
__global__ __launch_bounds__(512, 4) void fused_kernel(
    const float* __restrict__ feat, const float* __restrict__ W,
    const float* __restrict__ a,    const float* __restrict__ adj,
    unsigned short* __restrict__ hT, float* __restrict__ s_g,
    float* __restrict__ t_g, float* __restrict__ out)
{
    __shared__ __align__(16) char smem[49152];
    unsigned short* Wt  = (unsigned short*)smem;             // P1: 32 KB
    unsigned short* flb = (unsigned short*)(smem + 32768);   // P1: 16 KB bf16[64][128]
    unsigned short* ht  = (unsigned short*)smem;             // P2: 18432 B
    unsigned short* pt  = (unsigned short*)(smem + 18432);   // P2:  9216 B
    float*          tl  = (float*)(smem + 27648);            // P2:  4096 B
    float*          sl  = (float*)(smem + 31744);            // P2:   256 B
    float*          rsl = (float*)(smem + 32000);            // P2:   256 B

    const int tid = threadIdx.x;
    const int blk = ((int)blockIdx.x & 7) * 64 + ((int)blockIdx.x >> 3);
    const int b   = blk >> 4;
    const int i0  = (blk & 15) * 64;
    const long row0 = (long)blk * 64;

    // phase-2 ids needed early (adj prefetch)
    const int gi = tid >> 3;
    const int gj = (tid & 7) * 8;
    const float* arow = adj + ((size_t)(b * N_ + i0 + gi)) * N_ + gj;
    float4 a_reg[2][2];
#define LOAD_A(K) do {                                                         \
    a_reg[(K) & 1][0] = *reinterpret_cast<const float4*>(arow + (K) * 64);     \
    a_reg[(K) & 1][1] = *reinterpret_cast<const float4*>(arow + (K) * 64 + 4); \
} while (0)

    // ================= PHASE 1 =================
    for (int i = tid; i < 128 * 128; i += 512) {
        int d = i >> 7, k = i & 127;
        Wt[k * 128 + d] = bf16b(W[i]);
    }
    for (int i = tid; i < 64 * 128; i += 512) {
        int r = i >> 7, k = i & 127;
        flb[r * 128 + ((k + 8 * (r >> 2)) & 127)] = bf16b(feat[(row0 + r) * 128 + k]);
    }
    __syncthreads();

    LOAD_A(0);                // adj stream starts under the GEMM
    LOAD_A(1);

    const int oct = tid & 15;
    const int rg  = tid >> 4;      // [0,32)
    const int d0  = oct * 8;
    const int r0  = rg * 2;        // 2 rows/thread

    float acc1[2][8];
    #pragma unroll
    for (int q = 0; q < 2; ++q)
        #pragma unroll
        for (int c = 0; c < 8; ++c) acc1[q][c] = 0.f;

    for (int kc = 0; kc < 128; kc += 4) {
        float wv[4][8];
        #pragma unroll
        for (int kk = 0; kk < 4; ++kk) {
            short8_t wr = *reinterpret_cast<const short8_t*>(&Wt[(kc + kk) * 128 + d0]);
            #pragma unroll
            for (int c = 0; c < 8; ++c) wv[kk][c] = bf2f((unsigned short)wr[c]);
        }
        #pragma unroll
        for (int q = 0; q < 2; ++q) {
            int r = r0 + q;
            int koff = (kc + 8 * (r >> 2)) & 127;
            short4_t fv = *reinterpret_cast<const short4_t*>(&flb[r * 128 + koff]);
            float fq[4];
            #pragma unroll
            for (int e = 0; e < 4; ++e) fq[e] = bf2f((unsigned short)fv[e]);
            #pragma unroll
            for (int kk = 0; kk < 4; ++kk)
                #pragma unroll
                for (int c = 0; c < 8; ++c)
                    acc1[q][c] = fmaf(fq[kk], wv[kk][c], acc1[q][c]);
        }
    }

    {
        float asrc[8], adst[8];
        #pragma unroll
        for (int c = 0; c < 8; ++c) { asrc[c] = a[d0 + c]; adst[c] = a[128 + d0 + c]; }
        #pragma unroll
        for (int q = 0; q < 2; ++q) {
            long row = row0 + r0 + q;
            float sv = 0.f, tv = 0.f;
            #pragma unroll
            for (int c = 0; c < 8; ++c) {
                sv = fmaf(acc1[q][c], asrc[c], sv);
                tv = fmaf(acc1[q][c], adst[c], tv);
            }
            #pragma unroll
            for (int off = 1; off < 16; off <<= 1) {
                sv += __shfl_xor(sv, off);
                tv += __shfl_xor(tv, off);
            }
            if (oct == 0) { s_g[row] = sv; t_g[row] = tv; }
        }
    }

    // in-LDS transpose: flb reused as [j][swizzled d] bf16
    __syncthreads();
    #pragma unroll
    for (int q = 0; q < 2; ++q) {
        int r = r0 + q;
        int base0 = (d0 + 4 * (r >> 2)) & 127;
        int base1 = (d0 + 4 + 4 * (r >> 2)) & 127;
        short4_t p0, p1;
        #pragma unroll
        for (int e = 0; e < 4; ++e) {
            p0[e] = (short)bf16b(acc1[q][e]);
            p1[e] = (short)bf16b(acc1[q][4 + e]);
        }
        *reinterpret_cast<short4_t*>(&flb[r * 128 + base0]) = p0;
        *reinterpret_cast<short4_t*>(&flb[r * 128 + base1]) = p1;
    }
    __syncthreads();

    // coalesced hT write: thread -> d = tid>>2, j-quarter = tid&3 (16 j's)
    {
        const int d  = tid >> 2;
        const int qg = tid & 3;
        unsigned short* dst = hT + ((size_t)b * F_ + d) * N_ + i0 + qg * 16;
        #pragma unroll
        for (int qq = 0; qq < 2; ++qq) {
            short8_t pk;
            #pragma unroll
            for (int e = 0; e < 8; ++e) {
                int j = qg * 16 + qq * 8 + e;
                pk[e] = (short)flb[j * 128 + ((d + 4 * (j >> 2)) & 127)];
            }
            *reinterpret_cast<short8_t*>(dst + qq * 8) = pk;
        }
    }

    __threadfence();
    cg::this_grid().sync();

    // ================= PHASE 2 (R11-proven body) =================
    tl[tid]       = t_g[b * N_ + tid];
    tl[tid + 512] = t_g[b * N_ + tid + 512];
    if (tid < 64) sl[tid] = s_g[b * N_ + i0 + tid];

    const unsigned short* hTb = hT + (size_t)b * F_ * N_;
    short8_t h_reg[2][2];
#define LOAD_H(K) do {                                                         \
    _Pragma("unroll")                                                          \
    for (int c = 0; c < 2; ++c) {                                              \
        int ch = tid + c * 512;                                                \
        h_reg[(K) & 1][c] = *reinterpret_cast<const short8_t*>(                \
            hTb + (size_t)(ch >> 3) * N_ + ((K) * 64 + (ch & 7) * 8));         \
    }                                                                          \
} while (0)

    const int w  = tid >> 6;
    const int m0 = (w >> 2) * 32;
    const int n0 = (w & 3) * 32;
    const int lm = tid & 15;
    const int kg = (tid & 63) >> 4;

    f32x4 acc[2][2];
    #pragma unroll
    for (int nf = 0; nf < 2; ++nf)
        #pragma unroll
        for (int mf = 0; mf < 2; ++mf) acc[nf][mf] = (f32x4){0.f, 0.f, 0.f, 0.f};
    float rs = 0.f;

    LOAD_H(0);
    WAIT_LGKM();
    SCHEDB();
    BAR();
    const float s_i = sl[gi];

    #pragma unroll
    for (int k = 0; k < 16; ++k) {
        if (k + 1 < 16) LOAD_H(k + 1);
        #pragma unroll
        for (int c = 0; c < 2; ++c) {
            int ch = tid + c * 512;
            *reinterpret_cast<short8_t*>(&ht[(ch >> 3) * PSTR + (ch & 7) * 8]) =
                h_reg[k & 1][c];
        }
        {
            float4 a0 = a_reg[k & 1][0];
            float4 a1 = a_reg[k & 1][1];
            float4 t0 = *reinterpret_cast<const float4*>(&tl[k * 64 + gj]);
            float4 t1 = *reinterpret_cast<const float4*>(&tl[k * 64 + gj + 4]);
            short4_t pk0, pk1;
            #pragma unroll
            for (int e = 0; e < 4; ++e) {
                float sc0 = s_i + (&t0.x)[e];
                sc0 = fmaxf(sc0, ALPHA_ * sc0);
                float p = __expf(sc0) * (&a0.x)[e];
                rs += p;
                pk0[e] = (short)bf16b(p);
            }
            #pragma unroll
            for (int e = 0; e < 4; ++e) {
                float sc1 = s_i + (&t1.x)[e];
                sc1 = fmaxf(sc1, ALPHA_ * sc1);
                float p = __expf(sc1) * (&a1.x)[e];
                rs += p;
                pk1[e] = (short)bf16b(p);
            }
            *reinterpret_cast<short4_t*>(&pt[gi * PSTR + gj])     = pk0;
            *reinterpret_cast<short4_t*>(&pt[gi * PSTR + gj + 4]) = pk1;
        }
        if (k + 2 < 16) LOAD_A(k + 2);     // refill just-consumed slot
        WAIT_LGKM();
        SCHEDB();
        BAR();
        #pragma unroll
        for (int ks = 0; ks < 2; ++ks) {
            short8_t b0 = *reinterpret_cast<const short8_t*>(
                &ht[(n0 + lm) * PSTR + ks * 32 + kg * 8]);
            short8_t b1 = *reinterpret_cast<const short8_t*>(
                &ht[(n0 + 16 + lm) * PSTR + ks * 32 + kg * 8]);
            short8_t a0f = *reinterpret_cast<const short8_t*>(
                &pt[(m0 + lm) * PSTR + ks * 32 + kg * 8]);
            short8_t a1f = *reinterpret_cast<const short8_t*>(
                &pt[(m0 + 16 + lm) * PSTR + ks * 32 + kg * 8]);
            acc[0][0] = __builtin_amdgcn_mfma_f32_16x16x32_bf16(a0f, b0, acc[0][0], 0, 0, 0);
            acc[1][0] = __builtin_amdgcn_mfma_f32_16x16x32_bf16(a0f, b1, acc[1][0], 0, 0, 0);
            acc[0][1] = __builtin_amdgcn_mfma_f32_16x16x32_bf16(a1f, b0, acc[0][1], 0, 0, 0);
            acc[1][1] = __builtin_amdgcn_mfma_f32_16x16x32_bf16(a1f, b1, acc[1][1], 0, 0, 0);
        }
        BAR();
    }

    rs += __shfl_xor(rs, 1);
    rs += __shfl_xor(rs, 2);
    rs += __shfl_xor(rs, 4);
    if ((tid & 7) == 0) rsl[gi] = 1.0f / rs;
    __syncthreads();

    const int rbase = m0 + ((tid & 63) >> 4) * 4;
    float* ob = out + ((size_t)(b * N_ + i0)) * F_;
    #pragma unroll
    for (int mf = 0; mf < 2; ++mf) {
        f32x4 inv = *reinterpret_cast<const f32x4*>(&rsl[rbase + mf * 16]);
        #pragma unroll
        for (int r = 0; r < 4; ++r) {
            int row = rbase + mf * 16 + r;
            #pragma unroll
            for (int nf = 0; nf < 2; ++nf)
                ob[(size_t)row * F_ + n0 + nf * 16 + lm] = acc[nf][mf][r] * inv[r];
        }
    }
#undef LOAD_A
#undef LOAD_H
}

// ===========================================================================
// FALLBACK path: R11-proven two-kernel pipeline (verbatim).
// ===========================================================================
__global__ __launch_bounds__(256) void hst_kernel(
    const float* __restrict__ feat, const float* __restrict__ W,
    const float* __restrict__ a, unsigned short* __restrict__ hT,
    float* __restrict__ s_out, float* __restrict__ t_out)
{
    __shared__ unsigned short Wt[128 * 128];
    __shared__ float fl[64 * 128];
    const int tid = threadIdx.x;
    const long row0 = (long)blockIdx.x * 64;
    const int b  = (int)(row0 >> 10);
    const int jb = (int)(row0 & 1023);

    for (int i = tid; i < 128 * 128; i += 256) {
        int d = i >> 7, k = i & 127;
        Wt[k * 128 + d] = bf16b(W[i]);
    }
    for (int i = tid; i < 64 * 128; i += 256) {
        int r = i >> 7, k = i & 127;
        fl[r * 128 + ((k + 8 * (r >> 2)) & 127)] = feat[(row0 + r) * 128 + k];
    }
    __syncthreads();

    const int oct = tid & 15;
    const int rg  = tid >> 4;
    const int d0  = oct * 8;
    const int r0  = rg * 4;

    float acc[4][8];
    #pragma unroll
    for (int q = 0; q < 4; ++q)
        #pragma unroll
        for (int c = 0; c < 8; ++c) acc[q][c] = 0.f;

    for (int kc = 0; kc < 128; kc += 4) {
        float wv[4][8];
        #pragma unroll
        for (int kk = 0; kk < 4; ++kk) {
            short8_t wr = *reinterpret_cast<const short8_t*>(&Wt[(kc + kk) * 128 + d0]);
            #pragma unroll
            for (int c = 0; c < 8; ++c) wv[kk][c] = bf2f((unsigned short)wr[c]);
        }
        #pragma unroll
        for (int q = 0; q < 4; ++q) {
            int r = r0 + q;
            int koff = (kc + 8 * (r >> 2)) & 127;
            float4 fv = *reinterpret_cast<const float4*>(&fl[r * 128 + koff]);
            float fq[4] = {fv.x, fv.y, fv.z, fv.w};
            #pragma unroll
            for (int kk = 0; kk < 4; ++kk)
                #pragma unroll
                for (int c = 0; c < 8; ++c)
                    acc[q][c] = fmaf(fq[kk], wv[kk][c], acc[q][c]);
        }
    }

    float asrc[8], adst[8];
    #pragma unroll
    for (int c = 0; c < 8; ++c) { asrc[c] = a[d0 + c]; adst[c] = a[128 + d0 + c]; }
    #pragma unroll
    for (int q = 0; q < 4; ++q) {
        long row = row0 + r0 + q;
        float sv = 0.f, tv = 0.f;
        #pragma unroll
        for (int c = 0; c < 8; ++c) {
            sv = fmaf(acc[q][c], asrc[c], sv);
            tv = fmaf(acc[q][c], adst[c], tv);
        }
        #pragma unroll
        for (int off = 1; off < 16; off <<= 1) {
            sv += __shfl_xor(sv, off);
            tv += __shfl_xor(tv, off);
        }
        if (oct == 0) { s_out[row] = sv; t_out[row] = tv; }
    }

    __syncthreads();
    #pragma unroll
    for (int q = 0; q < 4; ++q) {
        int r = r0 + q;
        int base0 = (d0 + 4 * rg) & 127;
        int base1 = (d0 + 4 + 4 * rg) & 127;
        *reinterpret_cast<float4*>(&fl[r * 128 + base0]) =
            make_float4(acc[q][0], acc[q][1], acc[q][2], acc[q][3]);
        *reinterpret_cast<float4*>(&fl[r * 128 + base1]) =
            make_float4(acc[q][4], acc[q][5], acc[q][6], acc[q][7]);
    }
    __syncthreads();

    {
        const int d    = tid >> 1;
        const int half = tid & 1;
        unsigned short* dst = hT + ((size_t)b * F_ + d) * N_ + jb + half * 32;
        #pragma unroll
        for (int qq = 0; qq < 4; ++qq) {
            short8_t pk;
            #pragma unroll
            for (int e = 0; e < 8; ++e) {
                int j = half * 32 + qq * 8 + e;
                pk[e] = (short)bf16b(fl[j * 128 + ((d + 4 * (j >> 2)) & 127)]);
            }
            *reinterpret_cast<short8_t*>(dst + qq * 8) = pk;
        }
    }
}

__global__ __launch_bounds__(512, 4) void attn5_kernel(
    const float* __restrict__ adj, const unsigned short* __restrict__ hT,
    const float* __restrict__ s_in, const float* __restrict__ t_in,
    float* __restrict__ out)
{
    __shared__ unsigned short ht[128 * PSTR];
    __shared__ unsigned short pt[64 * PSTR];
    __shared__ float tl[N_];
    __shared__ float sl[64], rsl[64];

    const int tid = threadIdx.x;
    const int w   = tid >> 6;

    const int blk = (blockIdx.x & 7) * 64 + (blockIdx.x >> 3);
    const int b   = blk >> 4;
    const int i0  = (blk & 15) * 64;

    tl[tid]       = t_in[b * N_ + tid];
    tl[tid + 512] = t_in[b * N_ + tid + 512];
    if (tid < 64) sl[tid] = s_in[b * N_ + i0 + tid];

    const int gi = tid >> 3;
    const int gj = (tid & 7) * 8;
    const float* arow = adj + ((size_t)(b * N_ + i0 + gi)) * N_ + gj;

    const unsigned short* hTb = hT + (size_t)b * F_ * N_;

    float4   a_reg[2][2];
    short8_t h_reg[2][2];
#define LOAD_A(K) do {                                                         \
    a_reg[(K) & 1][0] = *reinterpret_cast<const float4*>(arow + (K) * 64);     \
    a_reg[(K) & 1][1] = *reinterpret_cast<const float4*>(arow + (K) * 64 + 4); \
} while (0)
#define LOAD_H(K) do {                                                         \
    _Pragma("unroll")                                                          \
    for (int c = 0; c < 2; ++c) {                                              \
        int ch = tid + c * 512;                                                \
        h_reg[(K) & 1][c] = *reinterpret_cast<const short8_t*>(                \
            hTb + (size_t)(ch >> 3) * N_ + ((K) * 64 + (ch & 7) * 8));         \
    }                                                                          \
} while (0)

    const int m0 = (w >> 2) * 32;
    const int n0 = (w & 3) * 32;
    const int lm = tid & 15;
    const int kg = (tid & 63) >> 4;

    f32x4 acc[2][2];
    #pragma unroll
    for (int nf = 0; nf < 2; ++nf)
        #pragma unroll
        for (int mf = 0; mf < 2; ++mf) acc[nf][mf] = (f32x4){0.f, 0.f, 0.f, 0.f};
    float rs = 0.f;

    LOAD_A(0);
    LOAD_H(0);
    WAIT_LGKM();
    SCHEDB();
    BAR();
    const float s_i = sl[gi];

    #pragma unroll
    for (int k = 0; k < 16; ++k) {
        if (k + 1 < 16) { LOAD_A(k + 1); LOAD_H(k + 1); }
        #pragma unroll
        for (int c = 0; c < 2; ++c) {
            int ch = tid + c * 512;
            *reinterpret_cast<short8_t*>(&ht[(ch >> 3) * PSTR + (ch & 7) * 8]) =
                h_reg[k & 1][c];
        }
        {
            float4 a0 = a_reg[k & 1][0];
            float4 a1 = a_reg[k & 1][1];
            float4 t0 = *reinterpret_cast<const float4*>(&tl[k * 64 + gj]);
            float4 t1 = *reinterpret_cast<const float4*>(&tl[k * 64 + gj + 4]);
            short4_t pk0, pk1;
            #pragma unroll
            for (int e = 0; e < 4; ++e) {
                float sc0 = s_i + (&t0.x)[e];
                sc0 = fmaxf(sc0, ALPHA_ * sc0);
                float p = __expf(sc0) * (&a0.x)[e];
                rs += p;
                pk0[e] = (short)bf16b(p);
            }
            #pragma unroll
            for (int e = 0; e < 4; ++e) {
                float sc1 = s_i + (&t1.x)[e];
                sc1 = fmaxf(sc1, ALPHA_ * sc1);
                float p = __expf(sc1) * (&a1.x)[e];
                rs += p;
                pk1[e] = (short)bf16b(p);
            }
            *reinterpret_cast<short4_t*>(&pt[gi * PSTR + gj])     = pk0;
            *reinterpret_cast<short4_t*>(&pt[gi * PSTR + gj + 4]) = pk1;
        }
        WAIT_LGKM();
        SCHEDB();
        BAR();
        #pragma unroll
        for (int ks = 0; ks < 2; ++ks) {
            short8_t b0 = *reinterpret_cast<const short8_t*>(
                &ht[(n0 + lm) * PSTR + ks * 32 + kg * 8]);
            short8_t b1 = *reinterpret_cast<const short8_t*>(
                &ht[(n0 + 16 + lm) * PSTR + ks * 32 + kg * 8]);
            short8_t a0f = *reinterpret_cast<const short8_t*>(
                &pt[(m0 + lm) * PSTR + ks * 32 + kg * 8]);
            short8_t a1f = *reinterpret_cast<const short8_t*>(
                &pt[(m0 + 16 + lm) * PSTR + ks * 32 + kg * 8]);
            acc[0][0] = __builtin_amdgcn_mfma_f32_16x16x32_bf16(a0f, b0, acc[0][0], 0, 0, 0);
            acc[1][0] = __builtin_amdgcn_mfma_f32_16x16x32_bf16(a0f, b1, acc[1][0], 0, 0, 0);
            acc[0][1] = __builtin_amdgcn_mfma_f32_16x16x32_bf16(a1f, b0, acc[0][1], 0, 0, 0);
            acc[1][1] = __builtin_amdgcn_mfma_f32_16x16x32_bf16(a1f, b1, acc[1][1], 0, 0, 0);
        }
        BAR();
    }

    rs += __shfl_xor(rs, 1);
    rs += __shfl_xor(rs, 2);
    rs += __shfl_xor(rs, 4);
    if ((tid & 7) == 0) rsl[gi] = 1.0f / rs;
    __syncthreads();

    const int rbase = m0 + ((tid & 63) >> 4) * 4;
    float* ob = out + ((size_t)(b * N_ + i0)) * F_;
    #pragma unroll
    for (int mf = 0; mf < 2; ++mf) {
        f32x4 inv = *reinterpret_cast<const f32x4*>(&rsl[rbase + mf * 16]);
        #pragma unroll
        for (int r = 0; r < 4; ++r) {
            int row = rbase + mf * 16 + r;
            #pragma unroll
            for (int nf = 0; nf < 2; ++nf)
                ob[(size_t)row * F_ + n0 + nf * 16 + lm] = acc[nf][mf][r] * inv[r];
        }
    }
#undef LOAD_A
#undef LOAD_H
}

// ---------------------------------------------------------------------------
extern "C" void kernel_launch(void* const* d_in, const int* in_sizes, int n_in,
                              void* d_out, int out_size, void* d_ws, size_t ws_size,
                              hipStream_t stream)
{
    const float* adj  = (const float*)d_in[0];   // (32,1024,1024)
    const float* feat = (const float*)d_in[1];   // (32,1024,128)
    const float* W    = (const float*)d_in[2];   // (128,128)
    const float* a    = (const float*)d_in[3];   // (256,1)
    float* out = (float*)d_out;                  // (32,1024,128) fp32

    unsigned short* hT = (unsigned short*)d_ws;                          // 8 MB
    float* s = (float*)((char*)d_ws + (size_t)B_ * F_ * N_ * 2);         // 128 KB
    float* t = s + (size_t)B_ * N_;                                      // 128 KB

    void* args[] = { (void*)&feat, (void*)&W, (void*)&a, (void*)&adj,
                     (void*)&hT, (void*)&s, (void*)&t, (void*)&out };
    hipError_t err = hipLaunchCooperativeKernel(
        (const void*)fused_kernel, dim3(B_ * 16), dim3(512), args, 0, stream);
    if (err != hipSuccess) {
        // deterministic fallback: R11-proven two-kernel path (same math)
        hst_kernel<<<(B_ * N_) / 64, 256, 0, stream>>>(feat, W, a, hT, s, t);
        attn5_kernel<<<B_ * 16, 512, 0, stream>>>(adj, hT, s, t, out);
    }
}

// Round 14
// 62.296 us; speedup vs baseline: 3.5120x; 3.5120x over previous
//
#include <hip/hip_runtime.h>
#include <hip/hip_bf16.h>

#define B_ 32
#define N_ 1024
#define F_ 128
#define ALPHA_ 0.2f
#define PSTR 72   // padded LDS row stride in bf16 elems (144 B = 9 x 16B slots)

typedef __attribute__((ext_vector_type(8))) short short8_t;
typedef __attribute__((ext_vector_type(4))) short short4_t;
typedef __attribute__((ext_vector_type(4))) float f32x4;

static __device__ __forceinline__ unsigned short bf16b(float f) {
    return __bfloat16_as_ushort(__float2bfloat16(f));
}

#define WAIT_LGKM() asm volatile("s_waitcnt lgkmcnt(0)" ::: "memory")
#define SCHEDB()    __builtin_amdgcn_sched_barrier(0)
#define BAR()       __builtin_amdgcn_s_barrier()

// ---------------------------------------------------------------------------
// Kernel A v2 (R9/R11-proven): hT = bf16(feat @ W^T) via in-LDS transpose;
// s = h@a_src; t = h@a_dst.
// ---------------------------------------------------------------------------
__global__ __launch_bounds__(256) void hst_kernel(
    const float* __restrict__ feat, const float* __restrict__ W,
    const float* __restrict__ a, unsigned short* __restrict__ hT,
    float* __restrict__ s_out, float* __restrict__ t_out)
{
    __shared__ unsigned short Wt[128 * 128];
    __shared__ float fl[64 * 128];
    const int tid = threadIdx.x;
    const long row0 = (long)blockIdx.x * 64;
    const int b  = (int)(row0 >> 10);
    const int jb = (int)(row0 & 1023);

    for (int i = tid; i < 128 * 128; i += 256) {
        int d = i >> 7, k = i & 127;
        Wt[k * 128 + d] = bf16b(W[i]);
    }
    for (int i = tid; i < 64 * 128; i += 256) {
        int r = i >> 7, k = i & 127;
        fl[r * 128 + ((k + 8 * (r >> 2)) & 127)] = feat[(row0 + r) * 128 + k];
    }
    __syncthreads();

    const int oct = tid & 15;
    const int rg  = tid >> 4;
    const int d0  = oct * 8;
    const int r0  = rg * 4;

    float acc[4][8];
    #pragma unroll
    for (int q = 0; q < 4; ++q)
        #pragma unroll
        for (int c = 0; c < 8; ++c) acc[q][c] = 0.f;

    for (int kc = 0; kc < 128; kc += 4) {
        float wv[4][8];
        #pragma unroll
        for (int kk = 0; kk < 4; ++kk) {
            short8_t wr = *reinterpret_cast<const short8_t*>(&Wt[(kc + kk) * 128 + d0]);
            #pragma unroll
            for (int c = 0; c < 8; ++c) {
                union { unsigned u; float f; } cv;
                cv.u = ((unsigned)(unsigned short)wr[c]) << 16;
                wv[kk][c] = cv.f;
            }
        }
        #pragma unroll
        for (int q = 0; q < 4; ++q) {
            int r = r0 + q;
            int koff = (kc + 8 * (r >> 2)) & 127;
            float4 fv = *reinterpret_cast<const float4*>(&fl[r * 128 + koff]);
            float fq[4] = {fv.x, fv.y, fv.z, fv.w};
            #pragma unroll
            for (int kk = 0; kk < 4; ++kk)
                #pragma unroll
                for (int c = 0; c < 8; ++c)
                    acc[q][c] = fmaf(fq[kk], wv[kk][c], acc[q][c]);
        }
    }

    float asrc[8], adst[8];
    #pragma unroll
    for (int c = 0; c < 8; ++c) { asrc[c] = a[d0 + c]; adst[c] = a[128 + d0 + c]; }
    #pragma unroll
    for (int q = 0; q < 4; ++q) {
        long row = row0 + r0 + q;
        float sv = 0.f, tv = 0.f;
        #pragma unroll
        for (int c = 0; c < 8; ++c) {
            sv = fmaf(acc[q][c], asrc[c], sv);
            tv = fmaf(acc[q][c], adst[c], tv);
        }
        #pragma unroll
        for (int off = 1; off < 16; off <<= 1) {
            sv += __shfl_xor(sv, off);
            tv += __shfl_xor(tv, off);
        }
        if (oct == 0) { s_out[row] = sv; t_out[row] = tv; }
    }

    // ---- in-LDS transpose: fl reused as [j][swizzled d] fp32 ----
    __syncthreads();
    #pragma unroll
    for (int q = 0; q < 4; ++q) {
        int r = r0 + q;
        int base0 = (d0 + 4 * rg) & 127;
        int base1 = (d0 + 4 + 4 * rg) & 127;
        *reinterpret_cast<float4*>(&fl[r * 128 + base0]) =
            make_float4(acc[q][0], acc[q][1], acc[q][2], acc[q][3]);
        *reinterpret_cast<float4*>(&fl[r * 128 + base1]) =
            make_float4(acc[q][4], acc[q][5], acc[q][6], acc[q][7]);
    }
    __syncthreads();

    {
        const int d    = tid >> 1;
        const int half = tid & 1;
        unsigned short* dst = hT + ((size_t)b * F_ + d) * N_ + jb + half * 32;
        #pragma unroll
        for (int qq = 0; qq < 4; ++qq) {
            short8_t pk;
            #pragma unroll
            for (int e = 0; e < 8; ++e) {
                int j = half * 32 + qq * 8 + e;
                pk[e] = (short)bf16b(fl[j * 128 + ((d + 4 * (j >> 2)) & 127)]);
            }
            *reinterpret_cast<short8_t*>(dst + qq * 8) = pk;
        }
    }
}

// ---------------------------------------------------------------------------
// Kernel B v9 (R9/R11-proven): fused MFMA attention, register-staged adj,
// dual-buffered prefetch, lgkm-only barriers.
// ---------------------------------------------------------------------------
__global__ __launch_bounds__(512, 4) void attn5_kernel(
    const float* __restrict__ adj, const unsigned short* __restrict__ hT,
    const float* __restrict__ s_in, const float* __restrict__ t_in,
    float* __restrict__ out)
{
    __shared__ unsigned short ht[128 * PSTR];     // 18 KB  [d][j]
    __shared__ unsigned short pt[64 * PSTR];      //  9 KB  [i][j]
    __shared__ float tl[N_];                      //  4 KB
    __shared__ float sl[64], rsl[64];

    const int tid = threadIdx.x;
    const int w   = tid >> 6;

    // XCD-chunked swizzle
    const int blk = (blockIdx.x & 7) * 64 + (blockIdx.x >> 3);
    const int b   = blk >> 4;
    const int i0  = (blk & 15) * 64;

    tl[tid]       = t_in[b * N_ + tid];
    tl[tid + 512] = t_in[b * N_ + tid + 512];
    if (tid < 64) sl[tid] = s_in[b * N_ + i0 + tid];

    const int gi = tid >> 3;
    const int gj = (tid & 7) * 8;
    const float* arow = adj + ((size_t)(b * N_ + i0 + gi)) * N_ + gj;

    const unsigned short* hTb = hT + (size_t)b * F_ * N_;

    float4   a_reg[2][2];    // [k&1][half]  — static after full unroll
    short8_t h_reg[2][2];    // [k&1][chunk]
#define LOAD_A(K) do {                                                         \
    a_reg[(K) & 1][0] = *reinterpret_cast<const float4*>(arow + (K) * 64);     \
    a_reg[(K) & 1][1] = *reinterpret_cast<const float4*>(arow + (K) * 64 + 4); \
} while (0)
#define LOAD_H(K) do {                                                         \
    _Pragma("unroll")                                                          \
    for (int c = 0; c < 2; ++c) {                                              \
        int ch = tid + c * 512;                                                \
        h_reg[(K) & 1][c] = *reinterpret_cast<const short8_t*>(                \
            hTb + (size_t)(ch >> 3) * N_ + ((K) * 64 + (ch & 7) * 8));         \
    }                                                                          \
} while (0)

    const int m0 = (w >> 2) * 32;
    const int n0 = (w & 3) * 32;
    const int lm = tid & 15;
    const int kg = (tid & 63) >> 4;

    f32x4 acc[2][2];
    #pragma unroll
    for (int nf = 0; nf < 2; ++nf)
        #pragma unroll
        for (int mf = 0; mf < 2; ++mf) acc[nf][mf] = (f32x4){0.f, 0.f, 0.f, 0.f};
    float rs = 0.f;

    // prologue: tile-0 loads in flight; LDS (tl/sl) visible to all
    LOAD_A(0);
    LOAD_H(0);
    WAIT_LGKM();
    SCHEDB();
    BAR();
    const float s_i = sl[gi];

    #pragma unroll
    for (int k = 0; k < 16; ++k) {
        // a. issue k+1 loads into the OTHER reg buffers (fly over everything)
        if (k + 1 < 16) { LOAD_A(k + 1); LOAD_H(k + 1); }
        // b. stage ht from h_reg[k&1] (compiler waits precisely on these regs)
        #pragma unroll
        for (int c = 0; c < 2; ++c) {
            int ch = tid + c * 512;
            *reinterpret_cast<short8_t*>(&ht[(ch >> 3) * PSTR + (ch & 7) * 8]) =
                h_reg[k & 1][c];
        }
        // c. P-gen straight from a_reg[k&1]
        {
            float4 a0 = a_reg[k & 1][0];
            float4 a1 = a_reg[k & 1][1];
            float4 t0 = *reinterpret_cast<const float4*>(&tl[k * 64 + gj]);
            float4 t1 = *reinterpret_cast<const float4*>(&tl[k * 64 + gj + 4]);
            short4_t pk0, pk1;
            #pragma unroll
            for (int e = 0; e < 4; ++e) {
                float sc0 = s_i + (&t0.x)[e];
                sc0 = fmaxf(sc0, ALPHA_ * sc0);
                float p = __expf(sc0) * (&a0.x)[e];   // adj is exactly 0.0/1.0
                rs += p;
                pk0[e] = (short)bf16b(p);
            }
            #pragma unroll
            for (int e = 0; e < 4; ++e) {
                float sc1 = s_i + (&t1.x)[e];
                sc1 = fmaxf(sc1, ALPHA_ * sc1);
                float p = __expf(sc1) * (&a1.x)[e];
                rs += p;
                pk1[e] = (short)bf16b(p);
            }
            *reinterpret_cast<short4_t*>(&pt[gi * PSTR + gj])     = pk0;
            *reinterpret_cast<short4_t*>(&pt[gi * PSTR + gj + 4]) = pk1;
        }
        // d. ht/pt visible to all waves (lgkm only — global loads keep flying)
        WAIT_LGKM();
        SCHEDB();
        BAR();
        // e. MFMA
        #pragma unroll
        for (int ks = 0; ks < 2; ++ks) {
            short8_t b0 = *reinterpret_cast<const short8_t*>(
                &ht[(n0 + lm) * PSTR + ks * 32 + kg * 8]);
            short8_t b1 = *reinterpret_cast<const short8_t*>(
                &ht[(n0 + 16 + lm) * PSTR + ks * 32 + kg * 8]);
            short8_t a0f = *reinterpret_cast<const short8_t*>(
                &pt[(m0 + lm) * PSTR + ks * 32 + kg * 8]);
            short8_t a1f = *reinterpret_cast<const short8_t*>(
                &pt[(m0 + 16 + lm) * PSTR + ks * 32 + kg * 8]);
            acc[0][0] = __builtin_amdgcn_mfma_f32_16x16x32_bf16(a0f, b0, acc[0][0], 0, 0, 0);
            acc[1][0] = __builtin_amdgcn_mfma_f32_16x16x32_bf16(a0f, b1, acc[1][0], 0, 0, 0);
            acc[0][1] = __builtin_amdgcn_mfma_f32_16x16x32_bf16(a1f, b0, acc[0][1], 0, 0, 0);
            acc[1][1] = __builtin_amdgcn_mfma_f32_16x16x32_bf16(a1f, b1, acc[1][1], 0, 0, 0);
        }
        // f. protect ht/pt overwrite next iter
        BAR();
    }

    // rowsum over the 8 threads sharing gi
    rs += __shfl_xor(rs, 1);
    rs += __shfl_xor(rs, 2);
    rs += __shfl_xor(rs, 4);
    if ((tid & 7) == 0) rsl[gi] = 1.0f / rs;
    __syncthreads();

    const int rbase = m0 + ((tid & 63) >> 4) * 4;
    float* ob = out + ((size_t)(b * N_ + i0)) * F_;
    #pragma unroll
    for (int mf = 0; mf < 2; ++mf) {
        f32x4 inv = *reinterpret_cast<const f32x4*>(&rsl[rbase + mf * 16]);
        #pragma unroll
        for (int r = 0; r < 4; ++r) {
            int row = rbase + mf * 16 + r;
            #pragma unroll
            for (int nf = 0; nf < 2; ++nf)
                ob[(size_t)row * F_ + n0 + nf * 16 + lm] = acc[nf][mf][r] * inv[r];
        }
    }
#undef LOAD_A
#undef LOAD_H
}

// ---------------------------------------------------------------------------
extern "C" void kernel_launch(void* const* d_in, const int* in_sizes, int n_in,
                              void* d_out, int out_size, void* d_ws, size_t ws_size,
                              hipStream_t stream)
{
    const float* adj  = (const float*)d_in[0];   // (32,1024,1024)
    const float* feat = (const float*)d_in[1];   // (32,1024,128)
    const float* W    = (const float*)d_in[2];   // (128,128)
    const float* a    = (const float*)d_in[3];   // (256,1)
    float* out = (float*)d_out;                  // (32,1024,128) fp32

    unsigned short* hT = (unsigned short*)d_ws;                          // 8 MB
    float* s = (float*)((char*)d_ws + (size_t)B_ * F_ * N_ * 2);         // 128 KB
    float* t = s + (size_t)B_ * N_;                                      // 128 KB

    hst_kernel<<<(B_ * N_) / 64, 256, 0, stream>>>(feat, W, a, hT, s, t);
    attn5_kernel<<<B_ * 16, 512, 0, stream>>>(adj, hT, s, t, out);
}